// Round 2
// 729.143 us; speedup vs baseline: 1.0543x; 1.0543x over previous
//
#include <hip/hip_runtime.h>

#define B_ 64
#define C_ 512
#define T_ 16
#define HW_ 196
#define K_ 8
#define D_ 49   // 7x7 pooled positions per channel
#define G_ 8    // channels per block in the atomic fallback path

// ============================================================================
// Path A: per-(b,c) partials in workspace (needs B_*C_*T_*4 + 4096 bytes)
// ============================================================================

// ---- pool 14x14 -> 7x7, per-(b,c) partial scores, NO atomics ----
__global__ __launch_bounds__(256) void pool_score_kernel(const float* __restrict__ x,
                                                         float* __restrict__ partial) {
    __shared__ float tile[T_ * HW_];   // 3136 floats = 12.25 KB
    __shared__ float pool[T_ * D_];    // 784
    __shared__ float ysum[D_];

    const unsigned bc = blockIdx.x;          // b*C_ + c
    const int tid = threadIdx.x;

    const float4* src4 = (const float4*)(x + (size_t)bc * (T_ * HW_));
    float4* tile4 = (float4*)tile;
    for (int i = tid; i < T_ * HW_ / 4; i += 256) tile4[i] = src4[i];
    __syncthreads();

    for (int i = tid; i < T_ * D_; i += 256) {
        int t  = i / 49;
        int pq = i - t * 49;
        int p  = pq / 7;
        int q  = pq - p * 7;
        int base = t * 196 + p * 28 + q * 2;
        pool[i] = 0.25f * (tile[base] + tile[base + 1] + tile[base + 14] + tile[base + 15]);
    }
    __syncthreads();

    if (tid < D_) {
        float s = 0.0f;
        #pragma unroll
        for (int t = 0; t < T_; ++t) s += pool[t * 49 + tid];
        ysum[tid] = s;
    }
    __syncthreads();

    const int t = tid >> 4;
    const int l = tid & 15;
    float acc = 0.0f;
    for (int pq = l; pq < D_; pq += 16) acc += pool[t * 49 + pq] * ysum[pq];
    acc += __shfl_xor(acc, 8);
    acc += __shfl_xor(acc, 4);
    acc += __shfl_xor(acc, 2);
    acc += __shfl_xor(acc, 1);
    if (l == 0) partial[(size_t)bc * T_ + t] = acc;
}

// ---- reduce partials over c, finalize, rank, emit sel. One block per b. ----
__global__ __launch_bounds__(256) void select_kernel_A(const float* __restrict__ partial,
                                                       int* __restrict__ sel) {
    __shared__ float part[256];   // [cg][t]
    __shared__ float S[T_];
    const int b = blockIdx.x;
    const int tid = threadIdx.x;
    const int t  = tid & 15;
    const int cg = tid >> 4;      // 16 channel groups of 32

    const float* P = partial + (size_t)b * C_ * T_;
    float s = 0.0f;
    for (int c = cg * 32; c < cg * 32 + 32; ++c) s += P[c * T_ + t];
    part[tid] = s;
    __syncthreads();

    if (tid < T_) {
        float tot = 0.0f;
        #pragma unroll
        for (int g = 0; g < 16; ++g) tot += part[g * 16 + tid];
        S[tid] = tot * (1.0f / (C_ * T_)) + ((tid & 1) ? 0.0f : 1.0f);
    }
    __syncthreads();

    if (tid < T_) {
        float vs = S[tid];
        int rd = 0, ra = 0;
        #pragma unroll
        for (int u = 0; u < T_; ++u) {
            float vu = S[u];
            rd += (vu > vs) || (vu == vs && u < tid);
            ra += (vu < vs) || (vu == vs && u < tid);
        }
        bool memA = rd < K_;
        bool memD = ra < K_;
        unsigned long long mA = __ballot(memA);
        unsigned long long mD = __ballot(memD);
        int posA = __popcll(mA & ((1ull << tid) - 1));
        int posD = __popcll(mD & ((1ull << tid) - 1));
        if (memA) sel[b * T_ + posA] = tid;
        if (memD) sel[b * T_ + K_ + posD] = tid;
    }
}

// ============================================================================
// Path B: 8 KB workspace fallback (proven layout), 8x fewer atomics than base
// ============================================================================

__global__ void zero_scores(float* __restrict__ score) {
    score[threadIdx.x] = 0.0f;   // 1024 = B_*T_ threads
}

// One block per (b, cg): accumulates G_ channels in LDS, one atomicAdd per t.
__global__ __launch_bounds__(256) void pool_score_atomic_kernel(const float* __restrict__ x,
                                                                float* __restrict__ score) {
    __shared__ float tile[T_ * HW_];
    __shared__ float pool[T_ * D_];
    __shared__ float ysum[D_];
    __shared__ float sacc[T_];

    const unsigned blk = blockIdx.x;         // b*(C_/G_) + cg
    const unsigned b   = blk / (C_ / G_);
    const unsigned cg  = blk % (C_ / G_);
    const int tid = threadIdx.x;

    if (tid < T_) sacc[tid] = 0.0f;

    for (int ci = 0; ci < G_; ++ci) {
        __syncthreads();   // guards sacc init / previous iter's pool reads
        const unsigned bc = b * C_ + cg * G_ + ci;
        const float4* src4 = (const float4*)(x + (size_t)bc * (T_ * HW_));
        float4* tile4 = (float4*)tile;
        for (int i = tid; i < T_ * HW_ / 4; i += 256) tile4[i] = src4[i];
        __syncthreads();

        for (int i = tid; i < T_ * D_; i += 256) {
            int t  = i / 49;
            int pq = i - t * 49;
            int p  = pq / 7;
            int q  = pq - p * 7;
            int base = t * 196 + p * 28 + q * 2;
            pool[i] = 0.25f * (tile[base] + tile[base + 1] + tile[base + 14] + tile[base + 15]);
        }
        __syncthreads();

        if (tid < D_) {
            float s = 0.0f;
            #pragma unroll
            for (int t = 0; t < T_; ++t) s += pool[t * 49 + tid];
            ysum[tid] = s;
        }
        __syncthreads();

        const int t = tid >> 4;
        const int l = tid & 15;
        float acc = 0.0f;
        for (int pq = l; pq < D_; pq += 16) acc += pool[t * 49 + pq] * ysum[pq];
        acc += __shfl_xor(acc, 8);
        acc += __shfl_xor(acc, 4);
        acc += __shfl_xor(acc, 2);
        acc += __shfl_xor(acc, 1);
        if (l == 0) sacc[t] += acc;          // single writer per t
    }
    __syncthreads();
    if (tid < T_) atomicAdd(&score[b * T_ + tid], sacc[tid]);
}

// Finalize from the dense score[b*T+t] array. One block of 1024 threads.
__global__ void select_kernel_B(const float* __restrict__ score, int* __restrict__ sel) {
    __shared__ float fs[B_ * T_];
    const int tid = threadIdx.x;
    const int b = tid >> 4;
    const int t = tid & 15;
    float v = score[tid] * (1.0f / (C_ * T_)) + ((t & 1) ? 0.0f : 1.0f);
    fs[tid] = v;
    __syncthreads();

    const float* S = fs + b * T_;
    float vs = S[t];
    int rd = 0, ra = 0;
    bool memA_t, memD_t;
    {
        for (int u = 0; u < T_; ++u) {
            float vu = S[u];
            rd += (vu > vs) || (vu == vs && u < t);
            ra += (vu < vs) || (vu == vs && u < t);
        }
        memA_t = rd < K_;
        memD_t = ra < K_;
    }
    if (memA_t) {
        int pos = 0;
        for (int s = 0; s < t; ++s) {
            float vu = S[s];
            int r = 0;
            for (int u = 0; u < T_; ++u) {
                float vv = S[u];
                r += (vv > vu) || (vv == vu && u < s);
            }
            pos += (r < K_);
        }
        sel[b * T_ + pos] = t;
    }
    if (memD_t) {
        int pos = 0;
        for (int s = 0; s < t; ++s) {
            float vu = S[s];
            int r = 0;
            for (int u = 0; u < T_; ++u) {
                float vv = S[u];
                r += (vv < vu) || (vv == vu && u < s);
            }
            pos += (r < K_);
        }
        sel[b * T_ + K_ + pos] = t;
    }
}

// ============================================================================
// shared gather
// ============================================================================
__global__ __launch_bounds__(256) void gather_kernel(const float* __restrict__ x,
                                                     const int* __restrict__ sel,
                                                     float* __restrict__ out) {
    const unsigned idx = blockIdx.x * 256u + threadIdx.x;  // over B_*C_*T_*49
    const unsigned q   = idx % 49u;
    const unsigned row = idx / 49u;
    const unsigned j   = row & 15u;
    const unsigned bc  = row >> 4;
    const unsigned b   = bc >> 9;

    const int t = sel[b * T_ + j];
    const float4* src = (const float4*)x + (size_t)(bc * T_ + t) * (HW_ / 4) + q;

    const unsigned halfOff = (unsigned)B_ * C_ * K_ * (HW_ / 4);
    float4* o4 = (float4*)out;
    unsigned dst = (j < K_)
        ? ((bc * K_ + j) * (HW_ / 4) + q)
        : (halfOff + (bc * K_ + (j - K_)) * (HW_ / 4) + q);
    o4[dst] = *src;
}

extern "C" void kernel_launch(void* const* d_in, const int* in_sizes, int n_in,
                              void* d_out, int out_size, void* d_ws, size_t ws_size,
                              hipStream_t stream) {
    const float* x = (const float*)d_in[0];
    float* out = (float*)d_out;

    const size_t partialBytes = (size_t)B_ * C_ * T_ * sizeof(float);  // 2 MB

    if (ws_size >= partialBytes + 4096) {
        // Path A: no atomics
        float* partial = (float*)d_ws;
        int*   sel     = (int*)((char*)d_ws + partialBytes);
        pool_score_kernel<<<B_ * C_, 256, 0, stream>>>(x, partial);
        select_kernel_A<<<B_, 256, 0, stream>>>(partial, sel);
        gather_kernel<<<(B_ * C_ * T_ * 49) / 256, 256, 0, stream>>>(x, sel, out);
    } else {
        // Path B: proven 8 KB layout, 8x fewer atomics than baseline
        float* score = (float*)d_ws;                 // 1024 floats
        int*   sel   = (int*)((char*)d_ws + 4096);   // 1024 ints
        zero_scores<<<1, B_ * T_, 0, stream>>>(score);
        pool_score_atomic_kernel<<<B_ * (C_ / G_), 256, 0, stream>>>(x, score);
        select_kernel_B<<<1, B_ * T_, 0, stream>>>(score, sel);
        gather_kernel<<<(B_ * C_ * T_ * 49) / 256, 256, 0, stream>>>(x, sel, out);
    }
}